// Round 3
// baseline (642.765 us; speedup 1.0000x reference)
//
#include <hip/hip_runtime.h>
#include <stdint.h>

// Problem constants: B=4, N=32768, K=16, nqueries=2048, stride=16.
// Geometry: one query PAIR per block (128 thr = 2 waves); each wave scans
// HALF the points (16384) for both queries; exact LDS merge of the two
// sorted top-16 lists at the end. 8192 waves total = 32/CU (occupancy cap).
#define NPTS  32768
#define NQ    2048
#define KNN   16
#define NB    4
#define BLOCK 128
#define WPB   2                     // waves per block (= halves of one pair)
#define PPL   8                     // points per lane per iteration
#define HALF  (NPTS / 2)            // 16384 points per wave
#define ITERS_H (HALF / (64 * PPL)) // 32

__device__ __forceinline__ int dpp_shr1_i(int x) {
    // row_shr:1 within 16-lane rows; row-start lane keeps old (bound_ctrl=0)
    return __builtin_amdgcn_update_dpp(x, x, 0x111, 0xf, 0xf, false);
}
__device__ __forceinline__ float dpp_shr1_f(float x) {
    return __int_as_float(dpp_shr1_i(__float_as_int(x)));
}
__device__ __forceinline__ float readlane_f(float x, int l) {
    return __int_as_float(__builtin_amdgcn_readlane(__float_as_int(x), l));
}

// Exact distributed top-16 for query T (0/1): sorted list (ascending by
// (dist,idx)) in lanes 16T..16T+15; lane 16T+15 holds the exact threshold tau.
// d is the EXACT numpy distance. tg = tau*(1+1e-5) is the conservative
// FMA-gate threshold (margin ~40x the fma-vs-numpy rounding gap).
template <int T>
__device__ __forceinline__ void insert_all(float d, int p, int lane,
                                           float& ld, int& li, float& tau, float& tg)
{
    unsigned long long rem = __ballot(d <= tau);
    while (rem) {
        const int srcl = __ffsll(rem) - 1;           // wave-uniform
        const float wd = readlane_f(d, srcl);
        const int   wi = __builtin_amdgcn_readlane(p, srcl);
        const bool less = (ld < wd) || (ld == wd && li < wi);
        const unsigned long long lm = __ballot(less);
        const int pos = __popc((unsigned)((lm >> (16 * T)) & 0xffffull));
        const float pld = dpp_shr1_f(ld);
        const int   pli = dpp_shr1_i(li);
        if ((lane >> 4) == T) {
            const int gl = lane & 15;
            if (gl == pos)      { ld = wd;  li = wi;  }
            else if (gl > pos)  { ld = pld; li = pli; }
        }
        tau = readlane_f(ld, 16 * T + 15);
        tg  = tau * 1.00001f;
        rem &= rem - 1;
        if (rem) rem &= __ballot(d <= tau);          // re-gate survivors (exact)
    }
}

__device__ __forceinline__ void load6(float4 dst[6], const float4* p) {
    #pragma unroll
    for (int t = 0; t < 6; ++t) dst[t] = p[t];
}

// One 512-point step: 8 pts/lane, 16 independent FMA-gate chains, exact
// recompute + exact insert for accepted slots.
__device__ __forceinline__ void step(const float4 c[6], int pb, int lane,
                                     float qx0, float qy0, float qz0,
                                     float qx1, float qy1, float qz1,
                                     float& ld, int& li,
                                     float& tau0, float& tau1,
                                     float& tg0, float& tg1)
{
    float px[PPL], py[PPL], pz[PPL];                 // pure register renames
    px[0] = c[0].x; py[0] = c[0].y; pz[0] = c[0].z;
    px[1] = c[0].w; py[1] = c[1].x; pz[1] = c[1].y;
    px[2] = c[1].z; py[2] = c[1].w; pz[2] = c[2].x;
    px[3] = c[2].y; py[3] = c[2].z; pz[3] = c[2].w;
    px[4] = c[3].x; py[4] = c[3].y; pz[4] = c[3].z;
    px[5] = c[3].w; py[5] = c[4].x; pz[5] = c[4].y;
    px[6] = c[4].z; py[6] = c[4].w; pz[6] = c[5].x;
    px[7] = c[5].y; py[7] = c[5].z; pz[7] = c[5].w;

    unsigned long long m0[PPL], m1[PPL], any = 0;
    #pragma unroll
    for (int j = 0; j < PPL; ++j) {                  // 16 independent chains
        const float ax = px[j] - qx0, ay = py[j] - qy0, az = pz[j] - qz0;
        const float g0 = __fmaf_rn(az, az, __fmaf_rn(ay, ay, __fmul_rn(ax, ax)));
        m0[j] = __ballot(g0 <= tg0);
        const float bx = px[j] - qx1, by = py[j] - qy1, bz = pz[j] - qz1;
        const float g1 = __fmaf_rn(bz, bz, __fmaf_rn(by, by, __fmul_rn(bx, bx)));
        m1[j] = __ballot(g1 <= tg1);
        any |= m0[j] | m1[j];
    }
    if (any) {
        #pragma unroll
        for (int j = 0; j < PPL; ++j) {
            if (m0[j]) {                             // exact numpy distance
                const float dx = __fadd_rn(px[j], -qx0);
                const float dy = __fadd_rn(py[j], -qy0);
                const float dz = __fadd_rn(pz[j], -qz0);
                const float d  = __fadd_rn(
                    __fadd_rn(__fmul_rn(dx, dx), __fmul_rn(dy, dy)),
                    __fmul_rn(dz, dz));
                insert_all<0>(d, pb + j, lane, ld, li, tau0, tg0);
            }
        }
        #pragma unroll
        for (int j = 0; j < PPL; ++j) {
            if (m1[j]) {
                const float dx = __fadd_rn(px[j], -qx1);
                const float dy = __fadd_rn(py[j], -qy1);
                const float dz = __fadd_rn(pz[j], -qz1);
                const float d  = __fadd_rn(
                    __fadd_rn(__fmul_rn(dx, dx), __fmul_rn(dy, dy)),
                    __fmul_rn(dz, dz));
                insert_all<1>(d, pb + j, lane, ld, li, tau1, tg1);
            }
        }
    }
}

// 4096 blocks x 2 waves = 8192 waves = 32/CU (occupancy cap).
// launch_bounds(128, 8) pins VGPR <= 64 so 8 waves/SIMD actually fit.
__global__ __launch_bounds__(BLOCK, 8) void knn_kernel(const float* __restrict__ xyz,
                                                       float* __restrict__ out_idx,
                                                       float* __restrict__ out_pts)
{
    const int tid  = threadIdx.x;
    const int lane = tid & 63;
    const int half = tid >> 6;               // which half of the point stream
    const int pair = blockIdx.x;             // query pair id in [0, 4096)
    const int b    = pair >> 10;
    const int pr   = pair & 1023;
    const size_t base = (size_t)b * NPTS * 3;

    const int qp0 = pr << 5;                 // stride-16 subsample
    const float qx0 = xyz[base + 3 * qp0 + 0];
    const float qy0 = xyz[base + 3 * qp0 + 1];
    const float qz0 = xyz[base + 3 * qp0 + 2];
    const float qx1 = xyz[base + 3 * qp0 + 48];
    const float qy1 = xyz[base + 3 * qp0 + 49];
    const float qz1 = xyz[base + 3 * qp0 + 50];

    const int g0 = b * NQ + (pr << 1);
    if (half == 0 && lane == 0) {
        out_pts[3 * g0 + 0] = qx0;
        out_pts[3 * g0 + 1] = qy0;
        out_pts[3 * g0 + 2] = qz0;
        out_pts[3 * g0 + 3] = qx1;
        out_pts[3 * g0 + 4] = qy1;
        out_pts[3 * g0 + 5] = qz1;
    }

    float ld = __builtin_inff();  int li = 0x7fffffff;
    float tau0 = __builtin_inff(), tau1 = __builtin_inff();
    float tg0  = __builtin_inff(), tg1  = __builtin_inff();

    // Lane's stream within this wave's half: 8 consecutive points per iter.
    const int pbase = half * HALF;
    const float4* lp = (const float4*)(xyz + base) + half * (HALF * 3 / 4) + 6 * lane;

    float4 A[6], Bf[6];
    load6(A, lp);                                    // prologue
    for (int k = 0; k < ITERS_H; k += 2) {           // double-buffered pipeline
        load6(Bf, lp + 384);                         // prefetch iter k+1
        step(A, pbase + (k << 9) + PPL * lane, lane,
             qx0, qy0, qz0, qx1, qy1, qz1, ld, li, tau0, tau1, tg0, tg1);
        if (k + 2 < ITERS_H)
            load6(A, lp + 768);                      // prefetch iter k+2
        step(Bf, pbase + ((k + 1) << 9) + PPL * lane, lane,
             qx0, qy0, qz0, qx1, qy1, qz1, ld, li, tau0, tau1, tg0, tg1);
        lp += 768;
    }

    // ---- exact merge of the two halves' sorted top-16 lists (per query) ----
    // Key order is lexicographic (d, idx); all idx distinct => strict total
    // order => merged position = own rank + #(strictly smaller in partner).
    __shared__ float sd[WPB * 32];
    __shared__ int   si[WPB * 32];
    if (lane < 32) {
        sd[(half << 5) + lane] = ld;
        si[(half << 5) + lane] = li;
    }
    __syncthreads();
    if (lane < 32) {
        const int T  = lane >> 4;                    // query within pair
        const int r  = lane & 15;                    // rank in own list
        const int pb2 = ((half ^ 1) << 5) + (T << 4);
        int cnt = 0;
        #pragma unroll
        for (int t = 0; t < 16; ++t) {               // broadcast reads (free)
            const float od = sd[pb2 + t];
            const int   oi = si[pb2 + t];
            cnt += (od < ld || (od == ld && oi < li)) ? 1 : 0;
        }
        const int pos = r + cnt;
        if (pos < KNN)
            out_idx[((size_t)(g0 + T)) * KNN + pos] = (float)li;
    }
}

extern "C" void kernel_launch(void* const* d_in, const int* in_sizes, int n_in,
                              void* d_out, int out_size, void* d_ws, size_t ws_size,
                              hipStream_t stream) {
    const float* xyz = (const float*)d_in[0];
    float* out = (float*)d_out;
    float* out_idx = out;                                 // NB*NQ*KNN floats
    float* out_pts = out + (size_t)NB * NQ * KNN;         // NB*NQ*3 floats

    const int blocks = NB * NQ / 2;                       // 4096 pairs
    knn_kernel<<<blocks, BLOCK, 0, stream>>>(xyz, out_idx, out_pts);
}

// Round 4
// 430.025 us; speedup vs baseline: 1.4947x; 1.4947x over previous
//
#include <hip/hip_runtime.h>
#include <stdint.h>

// Problem constants: B=4, N=32768, K=16, nqueries=2048, stride=16.
// Geometry: one query PAIR per block (128 thr = 2 waves); each wave scans
// HALF the points (16384) for both queries; exact LDS merge of the two
// sorted top-16 lists at the end. 8192 waves total = 32/CU (occupancy cap).
#define NPTS  32768
#define NQ    2048
#define KNN   16
#define NB    4
#define BLOCK 128
#define WPB   2                     // waves per block (= halves of one pair)
#define PPL   8                     // points per lane per iteration
#define HALF  (NPTS / 2)            // 16384 points per wave
#define ITERS_H (HALF / (64 * PPL)) // 32

__device__ __forceinline__ int dpp_shr1_i(int x) {
    // row_shr:1 within 16-lane rows; row-start lane keeps old (bound_ctrl=0)
    return __builtin_amdgcn_update_dpp(x, x, 0x111, 0xf, 0xf, false);
}
__device__ __forceinline__ float dpp_shr1_f(float x) {
    return __int_as_float(dpp_shr1_i(__float_as_int(x)));
}
__device__ __forceinline__ float readlane_f(float x, int l) {
    return __int_as_float(__builtin_amdgcn_readlane(__float_as_int(x), l));
}

// Exact distributed top-16 for query T (0/1): sorted list (ascending by
// (dist,idx)) in lanes 16T..16T+15; lane 16T+15 holds the exact threshold tau.
// d is the EXACT numpy distance. tg = tau*(1+1e-5) is the conservative
// FMA-gate threshold (margin ~40x the fma-vs-numpy rounding gap).
template <int T>
__device__ __forceinline__ void insert_all(float d, int p, int lane,
                                           float& ld, int& li, float& tau, float& tg)
{
    unsigned long long rem = __ballot(d <= tau);
    while (rem) {
        const int srcl = __ffsll(rem) - 1;           // wave-uniform
        const float wd = readlane_f(d, srcl);
        const int   wi = __builtin_amdgcn_readlane(p, srcl);
        const bool less = (ld < wd) || (ld == wd && li < wi);
        const unsigned long long lm = __ballot(less);
        const int pos = __popc((unsigned)((lm >> (16 * T)) & 0xffffull));
        const float pld = dpp_shr1_f(ld);
        const int   pli = dpp_shr1_i(li);
        if ((lane >> 4) == T) {
            const int gl = lane & 15;
            if (gl == pos)      { ld = wd;  li = wi;  }
            else if (gl > pos)  { ld = pld; li = pli; }
        }
        tau = readlane_f(ld, 16 * T + 15);
        tg  = tau * 1.00001f;
        rem &= rem - 1;
        if (rem) rem &= __ballot(d <= tau);          // re-gate survivors (exact)
    }
}

__device__ __forceinline__ void load6(float4 dst[6], const float4* p) {
    #pragma unroll
    for (int t = 0; t < 6; ++t) dst[t] = p[t];
}

// One 512-point step: 8 pts/lane, 16 independent FMA-gate chains, exact
// recompute + exact insert for accepted slots.
__device__ __forceinline__ void step(const float4 c[6], int pb, int lane,
                                     float qx0, float qy0, float qz0,
                                     float qx1, float qy1, float qz1,
                                     float& ld, int& li,
                                     float& tau0, float& tau1,
                                     float& tg0, float& tg1)
{
    float px[PPL], py[PPL], pz[PPL];                 // pure register renames
    px[0] = c[0].x; py[0] = c[0].y; pz[0] = c[0].z;
    px[1] = c[0].w; py[1] = c[1].x; pz[1] = c[1].y;
    px[2] = c[1].z; py[2] = c[1].w; pz[2] = c[2].x;
    px[3] = c[2].y; py[3] = c[2].z; pz[3] = c[2].w;
    px[4] = c[3].x; py[4] = c[3].y; pz[4] = c[3].z;
    px[5] = c[3].w; py[5] = c[4].x; pz[5] = c[4].y;
    px[6] = c[4].z; py[6] = c[4].w; pz[6] = c[5].x;
    px[7] = c[5].y; py[7] = c[5].z; pz[7] = c[5].w;

    unsigned long long m0[PPL], m1[PPL], any = 0;
    #pragma unroll
    for (int j = 0; j < PPL; ++j) {                  // 16 independent chains
        const float ax = px[j] - qx0, ay = py[j] - qy0, az = pz[j] - qz0;
        const float g0 = __fmaf_rn(az, az, __fmaf_rn(ay, ay, __fmul_rn(ax, ax)));
        m0[j] = __ballot(g0 <= tg0);
        const float bx = px[j] - qx1, by = py[j] - qy1, bz = pz[j] - qz1;
        const float g1 = __fmaf_rn(bz, bz, __fmaf_rn(by, by, __fmul_rn(bx, bx)));
        m1[j] = __ballot(g1 <= tg1);
        any |= m0[j] | m1[j];
    }
    if (any) {
        #pragma unroll
        for (int j = 0; j < PPL; ++j) {
            if (m0[j]) {                             // exact numpy distance
                const float dx = __fadd_rn(px[j], -qx0);
                const float dy = __fadd_rn(py[j], -qy0);
                const float dz = __fadd_rn(pz[j], -qz0);
                const float d  = __fadd_rn(
                    __fadd_rn(__fmul_rn(dx, dx), __fmul_rn(dy, dy)),
                    __fmul_rn(dz, dz));
                insert_all<0>(d, pb + j, lane, ld, li, tau0, tg0);
            }
        }
        #pragma unroll
        for (int j = 0; j < PPL; ++j) {
            if (m1[j]) {
                const float dx = __fadd_rn(px[j], -qx1);
                const float dy = __fadd_rn(py[j], -qy1);
                const float dz = __fadd_rn(pz[j], -qz1);
                const float d  = __fadd_rn(
                    __fadd_rn(__fmul_rn(dx, dx), __fmul_rn(dy, dy)),
                    __fmul_rn(dz, dz));
                insert_all<1>(d, pb + j, lane, ld, li, tau1, tg1);
            }
        }
    }
}

// 4096 blocks x 2 waves = 8192 waves = up to 32/CU.
// launch_bounds(128, 6): VGPR cap ~85 — enough headroom for the ~60-VGPR
// natural allocation (round-1 measured 60) so NOTHING spills; if the
// allocator lands <=64 the HW still reaches 8 waves/SIMD. (128,8) forced
// VGPR=32 and spilled 2.4 GB/dispatch to scratch — round-3 regression.
__global__ __launch_bounds__(BLOCK, 6) void knn_kernel(const float* __restrict__ xyz,
                                                       float* __restrict__ out_idx,
                                                       float* __restrict__ out_pts)
{
    const int tid  = threadIdx.x;
    const int lane = tid & 63;
    const int half = tid >> 6;               // which half of the point stream
    const int pair = blockIdx.x;             // query pair id in [0, 4096)
    const int b    = pair >> 10;
    const int pr   = pair & 1023;
    const size_t base = (size_t)b * NPTS * 3;

    const int qp0 = pr << 5;                 // stride-16 subsample
    const float qx0 = xyz[base + 3 * qp0 + 0];
    const float qy0 = xyz[base + 3 * qp0 + 1];
    const float qz0 = xyz[base + 3 * qp0 + 2];
    const float qx1 = xyz[base + 3 * qp0 + 48];
    const float qy1 = xyz[base + 3 * qp0 + 49];
    const float qz1 = xyz[base + 3 * qp0 + 50];

    const int g0 = b * NQ + (pr << 1);
    if (half == 0 && lane == 0) {
        out_pts[3 * g0 + 0] = qx0;
        out_pts[3 * g0 + 1] = qy0;
        out_pts[3 * g0 + 2] = qz0;
        out_pts[3 * g0 + 3] = qx1;
        out_pts[3 * g0 + 4] = qy1;
        out_pts[3 * g0 + 5] = qz1;
    }

    float ld = __builtin_inff();  int li = 0x7fffffff;
    float tau0 = __builtin_inff(), tau1 = __builtin_inff();
    float tg0  = __builtin_inff(), tg1  = __builtin_inff();

    // Lane's stream within this wave's half: 8 consecutive points per iter.
    const int pbase = half * HALF;
    const float4* lp = (const float4*)(xyz + base) + half * (HALF * 3 / 4) + 6 * lane;

    float4 A[6], Bf[6];
    load6(A, lp);                                    // prologue
    for (int k = 0; k < ITERS_H; k += 2) {           // double-buffered pipeline
        load6(Bf, lp + 384);                         // prefetch iter k+1
        step(A, pbase + (k << 9) + PPL * lane, lane,
             qx0, qy0, qz0, qx1, qy1, qz1, ld, li, tau0, tau1, tg0, tg1);
        if (k + 2 < ITERS_H)
            load6(A, lp + 768);                      // prefetch iter k+2
        step(Bf, pbase + ((k + 1) << 9) + PPL * lane, lane,
             qx0, qy0, qz0, qx1, qy1, qz1, ld, li, tau0, tau1, tg0, tg1);
        lp += 768;
    }

    // ---- exact merge of the two halves' sorted top-16 lists (per query) ----
    // Key order is lexicographic (d, idx); all idx distinct => strict total
    // order => merged position = own rank + #(strictly smaller in partner).
    __shared__ float sd[WPB * 32];
    __shared__ int   si[WPB * 32];
    if (lane < 32) {
        sd[(half << 5) + lane] = ld;
        si[(half << 5) + lane] = li;
    }
    __syncthreads();
    if (lane < 32) {
        const int T  = lane >> 4;                    // query within pair
        const int r  = lane & 15;                    // rank in own list
        const int pb2 = ((half ^ 1) << 5) + (T << 4);
        int cnt = 0;
        #pragma unroll
        for (int t = 0; t < 16; ++t) {               // broadcast reads (free)
            const float od = sd[pb2 + t];
            const int   oi = si[pb2 + t];
            cnt += (od < ld || (od == ld && oi < li)) ? 1 : 0;
        }
        const int pos = r + cnt;
        if (pos < KNN)
            out_idx[((size_t)(g0 + T)) * KNN + pos] = (float)li;
    }
}

extern "C" void kernel_launch(void* const* d_in, const int* in_sizes, int n_in,
                              void* d_out, int out_size, void* d_ws, size_t ws_size,
                              hipStream_t stream) {
    const float* xyz = (const float*)d_in[0];
    float* out = (float*)d_out;
    float* out_idx = out;                                 // NB*NQ*KNN floats
    float* out_pts = out + (size_t)NB * NQ * KNN;         // NB*NQ*3 floats

    const int blocks = NB * NQ / 2;                       // 4096 pairs
    knn_kernel<<<blocks, BLOCK, 0, stream>>>(xyz, out_idx, out_pts);
}

// Round 7
// 225.404 us; speedup vs baseline: 2.8516x; 1.9078x over previous
//
#include <hip/hip_runtime.h>
#include <stdint.h>

// Problem constants: B=4, N=32768, K=16, nqueries=2048, stride=16.
// Geometry: one query PAIR per block (128 thr = 2 waves); each wave scans
// HALF the points (16384) for both queries; exact LDS merge of the two
// sorted top-16 lists at the end. 8192 waves total -> 32/CU if VGPR<=64.
//
// Register budget: NO min-waves launch_bounds arg (with B=128 it was
// translated into 2x the intended wave pressure: (128,8)->VGPR32,
// (128,6)->VGPR40, both spilled ~1-2.4 GB scratch/dispatch). Instead,
// PPL=4 shrinks the double-buffer to 6 float4 (24 VGPR) so natural
// demand ~50 lands under the 64-VGPR / 8-waves-per-SIMD tier by itself.
#define NPTS  32768
#define NQ    2048
#define KNN   16
#define NB    4
#define BLOCK 128
#define WPB   2                     // waves per block (= halves of one pair)
#define PPL   4                     // points per lane per iteration
#define HALF  (NPTS / 2)            // 16384 points per wave
#define ITERS_H (HALF / (64 * PPL)) // 64

__device__ __forceinline__ int dpp_shr1_i(int x) {
    // row_shr:1 within 16-lane rows; row-start lane keeps old (bound_ctrl=0)
    return __builtin_amdgcn_update_dpp(x, x, 0x111, 0xf, 0xf, false);
}
__device__ __forceinline__ float dpp_shr1_f(float x) {
    return __int_as_float(dpp_shr1_i(__float_as_int(x)));
}
__device__ __forceinline__ float readlane_f(float x, int l) {
    return __int_as_float(__builtin_amdgcn_readlane(__float_as_int(x), l));
}

// Exact distributed top-16 for query T (0/1): sorted list (ascending by
// (dist,idx)) in lanes 16T..16T+15; lane 16T+15 holds the exact threshold tau.
// d is the EXACT numpy distance. tg = tau*(1+1e-5) is the conservative
// FMA-gate threshold (margin ~40x the fma-vs-numpy rounding gap).
template <int T>
__device__ __forceinline__ void insert_all(float d, int p, int lane,
                                           float& ld, int& li, float& tau, float& tg)
{
    unsigned long long rem = __ballot(d <= tau);
    while (rem) {
        const int srcl = __ffsll(rem) - 1;           // wave-uniform
        const float wd = readlane_f(d, srcl);
        const int   wi = __builtin_amdgcn_readlane(p, srcl);
        const bool less = (ld < wd) || (ld == wd && li < wi);
        const unsigned long long lm = __ballot(less);
        const int pos = __popc((unsigned)((lm >> (16 * T)) & 0xffffull));
        const float pld = dpp_shr1_f(ld);
        const int   pli = dpp_shr1_i(li);
        if ((lane >> 4) == T) {
            const int gl = lane & 15;
            if (gl == pos)      { ld = wd;  li = wi;  }
            else if (gl > pos)  { ld = pld; li = pli; }
        }
        tau = readlane_f(ld, 16 * T + 15);
        tg  = tau * 1.00001f;
        rem &= rem - 1;
        if (rem) rem &= __ballot(d <= tau);          // re-gate survivors (exact)
    }
}

__device__ __forceinline__ void load3(float4 dst[3], const float4* p) {
    #pragma unroll
    for (int t = 0; t < 3; ++t) dst[t] = p[t];
}

// One 256-point step: 4 pts/lane, 8 independent FMA-gate chains, exact
// recompute + exact insert for accepted slots.
__device__ __forceinline__ void step(const float4 c[3], int pb, int lane,
                                     float qx0, float qy0, float qz0,
                                     float qx1, float qy1, float qz1,
                                     float& ld, int& li,
                                     float& tau0, float& tau1,
                                     float& tg0, float& tg1)
{
    float px[PPL], py[PPL], pz[PPL];                 // pure register renames
    px[0] = c[0].x; py[0] = c[0].y; pz[0] = c[0].z;
    px[1] = c[0].w; py[1] = c[1].x; pz[1] = c[1].y;
    px[2] = c[1].z; py[2] = c[1].w; pz[2] = c[2].x;
    px[3] = c[2].y; py[3] = c[2].z; pz[3] = c[2].w;

    unsigned long long m0[PPL], m1[PPL], any = 0;
    #pragma unroll
    for (int j = 0; j < PPL; ++j) {                  // 8 independent chains
        const float ax = px[j] - qx0, ay = py[j] - qy0, az = pz[j] - qz0;
        const float g0 = __fmaf_rn(az, az, __fmaf_rn(ay, ay, __fmul_rn(ax, ax)));
        m0[j] = __ballot(g0 <= tg0);
        const float bx = px[j] - qx1, by = py[j] - qy1, bz = pz[j] - qz1;
        const float g1 = __fmaf_rn(bz, bz, __fmaf_rn(by, by, __fmul_rn(bx, bx)));
        m1[j] = __ballot(g1 <= tg1);
        any |= m0[j] | m1[j];
    }
    if (any) {
        #pragma unroll
        for (int j = 0; j < PPL; ++j) {
            if (m0[j]) {                             // exact numpy distance
                const float dx = __fadd_rn(px[j], -qx0);
                const float dy = __fadd_rn(py[j], -qy0);
                const float dz = __fadd_rn(pz[j], -qz0);
                const float d  = __fadd_rn(
                    __fadd_rn(__fmul_rn(dx, dx), __fmul_rn(dy, dy)),
                    __fmul_rn(dz, dz));
                insert_all<0>(d, pb + j, lane, ld, li, tau0, tg0);
            }
        }
        #pragma unroll
        for (int j = 0; j < PPL; ++j) {
            if (m1[j]) {
                const float dx = __fadd_rn(px[j], -qx1);
                const float dy = __fadd_rn(py[j], -qy1);
                const float dz = __fadd_rn(pz[j], -qz1);
                const float d  = __fadd_rn(
                    __fadd_rn(__fmul_rn(dx, dx), __fmul_rn(dy, dy)),
                    __fmul_rn(dz, dz));
                insert_all<1>(d, pb + j, lane, ld, li, tau1, tg1);
            }
        }
    }
}

// 4096 blocks x 2 waves = 8192 waves; VGPR<=64 (natural) -> 32 waves/CU.
__global__ __launch_bounds__(BLOCK) void knn_kernel(const float* __restrict__ xyz,
                                                    float* __restrict__ out_idx,
                                                    float* __restrict__ out_pts)
{
    const int tid  = threadIdx.x;
    const int lane = tid & 63;
    const int half = tid >> 6;               // which half of the point stream
    const int pair = blockIdx.x;             // query pair id in [0, 4096)
    const int b    = pair >> 10;
    const int pr   = pair & 1023;
    const size_t base = (size_t)b * NPTS * 3;

    const int qp0 = pr << 5;                 // stride-16 subsample
    const float qx0 = xyz[base + 3 * qp0 + 0];
    const float qy0 = xyz[base + 3 * qp0 + 1];
    const float qz0 = xyz[base + 3 * qp0 + 2];
    const float qx1 = xyz[base + 3 * qp0 + 48];
    const float qy1 = xyz[base + 3 * qp0 + 49];
    const float qz1 = xyz[base + 3 * qp0 + 50];

    const int g0 = b * NQ + (pr << 1);
    if (half == 0 && lane == 0) {
        out_pts[3 * g0 + 0] = qx0;
        out_pts[3 * g0 + 1] = qy0;
        out_pts[3 * g0 + 2] = qz0;
        out_pts[3 * g0 + 3] = qx1;
        out_pts[3 * g0 + 4] = qy1;
        out_pts[3 * g0 + 5] = qz1;
    }

    float ld = __builtin_inff();  int li = 0x7fffffff;
    float tau0 = __builtin_inff(), tau1 = __builtin_inff();
    float tg0  = __builtin_inff(), tg1  = __builtin_inff();

    // Lane's stream within this wave's half: 4 consecutive points per iter.
    const int pbase = half * HALF;
    const float4* lp = (const float4*)(xyz + base) + half * (HALF * 3 / 4) + 3 * lane;

    float4 A[3], Bf[3];
    load3(A, lp);                                    // prologue
    for (int k = 0; k < ITERS_H; k += 2) {           // double-buffered pipeline
        load3(Bf, lp + 192);                         // prefetch iter k+1
        step(A, pbase + (k << 8) + PPL * lane, lane,
             qx0, qy0, qz0, qx1, qy1, qz1, ld, li, tau0, tau1, tg0, tg1);
        if (k + 2 < ITERS_H)
            load3(A, lp + 384);                      // prefetch iter k+2
        step(Bf, pbase + ((k + 1) << 8) + PPL * lane, lane,
             qx0, qy0, qz0, qx1, qy1, qz1, ld, li, tau0, tau1, tg0, tg1);
        lp += 384;
    }

    // ---- exact merge of the two halves' sorted top-16 lists (per query) ----
    // Key order is lexicographic (d, idx); all idx distinct => strict total
    // order => merged position = own rank + #(strictly smaller in partner).
    __shared__ float sd[WPB * 32];
    __shared__ int   si[WPB * 32];
    if (lane < 32) {
        sd[(half << 5) + lane] = ld;
        si[(half << 5) + lane] = li;
    }
    __syncthreads();
    if (lane < 32) {
        const int T  = lane >> 4;                    // query within pair
        const int r  = lane & 15;                    // rank in own list
        const int pb2 = ((half ^ 1) << 5) + (T << 4);
        int cnt = 0;
        #pragma unroll
        for (int t = 0; t < 16; ++t) {               // broadcast reads (free)
            const float od = sd[pb2 + t];
            const int   oi = si[pb2 + t];
            cnt += (od < ld || (od == ld && oi < li)) ? 1 : 0;
        }
        const int pos = r + cnt;
        if (pos < KNN)
            out_idx[((size_t)(g0 + T)) * KNN + pos] = (float)li;
    }
}

extern "C" void kernel_launch(void* const* d_in, const int* in_sizes, int n_in,
                              void* d_out, int out_size, void* d_ws, size_t ws_size,
                              hipStream_t stream) {
    const float* xyz = (const float*)d_in[0];
    float* out = (float*)d_out;
    float* out_idx = out;                                 // NB*NQ*KNN floats
    float* out_pts = out + (size_t)NB * NQ * KNN;         // NB*NQ*3 floats

    const int blocks = NB * NQ / 2;                       // 4096 pairs
    knn_kernel<<<blocks, BLOCK, 0, stream>>>(xyz, out_idx, out_pts);
}

// Round 9
// 186.431 us; speedup vs baseline: 3.4477x; 1.2090x over previous
//
#include <hip/hip_runtime.h>
#include <stdint.h>

// Problem constants: B=4, N=32768, K=16, nqueries=2048, stride=16.
// Geometry (round-1, best measured 155us): 2 queries per wave, each wave
// scans the full 32768-point stream, 256-thr blocks, 4096 waves.
// Gate uses the dot-product expansion: d = |p|^2 - 2 p.q + |q|^2, so the
// test d<=tau becomes  s - 2 p.q <= tau - |q|^2. s=|p|^2 is SHARED by both
// queries (3 ops), each query adds 3 fma + 1 cmp: 11 ops/point vs 14.
// Gate is conservative (absolute margin 5e-4 >> 4e-5 fp-error bound);
// accepted lanes are re-verified with the EXACT numpy distance.
#define NPTS  32768
#define NQ    2048
#define KNN   16
#define NB    4
#define BLOCK 256
#define WPB   4               // waves per block; 2 queries per wave
#define PPL   8               // points per lane per iteration
#define ITERS (NPTS / (64 * PPL))   // 64
#define GATE_MARGIN 5e-4f

__device__ __forceinline__ int dpp_shr1_i(int x) {
    // row_shr:1 within 16-lane rows; row-start lane keeps old (bound_ctrl=0)
    return __builtin_amdgcn_update_dpp(x, x, 0x111, 0xf, 0xf, false);
}
__device__ __forceinline__ float dpp_shr1_f(float x) {
    return __int_as_float(dpp_shr1_i(__float_as_int(x)));
}
__device__ __forceinline__ float readlane_f(float x, int l) {
    return __int_as_float(__builtin_amdgcn_readlane(__float_as_int(x), l));
}

// Exact distributed top-16 for query T (0/1): sorted list (ascending by
// (dist,idx)) in lanes 16T..16T+15; lane 16T+15 holds the exact threshold
// tau. d is the EXACT numpy distance. th = tau + qnm is the conservative
// dot-product-gate threshold (qnm = -|q|^2 + margin).
template <int T>
__device__ __forceinline__ void insert_all(float d, int p, int lane,
                                           float& ld, int& li, float& tau,
                                           float& th, float qnm)
{
    unsigned long long rem = __ballot(d <= tau);
    while (rem) {
        const int srcl = __ffsll(rem) - 1;           // wave-uniform
        const float wd = readlane_f(d, srcl);
        const int   wi = __builtin_amdgcn_readlane(p, srcl);
        const bool less = (ld < wd) || (ld == wd && li < wi);
        const unsigned long long lm = __ballot(less);
        const int pos = __popc((unsigned)((lm >> (16 * T)) & 0xffffull));
        const float pld = dpp_shr1_f(ld);
        const int   pli = dpp_shr1_i(li);
        if ((lane >> 4) == T) {
            const int gl = lane & 15;
            if (gl == pos)      { ld = wd;  li = wi;  }
            else if (gl > pos)  { ld = pld; li = pli; }
        }
        tau = readlane_f(ld, 16 * T + 15);
        th  = tau + qnm;                             // gate threshold update
        rem &= rem - 1;
        if (rem) rem &= __ballot(d <= tau);          // re-gate survivors (exact)
    }
}

__device__ __forceinline__ void load6(float4 dst[6], const float4* p) {
    #pragma unroll
    for (int t = 0; t < 6; ++t) dst[t] = p[t];
}

// One 512-point step: 8 pts/lane; shared |p|^2 + per-query 3-fma gate;
// exact recompute + exact insert for accepted slots.
__device__ __forceinline__ void step(const float4 c[6], int pb, int lane,
                                     float m2x0, float m2y0, float m2z0,
                                     float m2x1, float m2y1, float m2z1,
                                     float qx0, float qy0, float qz0,
                                     float qx1, float qy1, float qz1,
                                     float& ld, int& li,
                                     float& tau0, float& tau1,
                                     float& th0, float& th1,
                                     float qnm0, float qnm1)
{
    float px[PPL], py[PPL], pz[PPL];                 // pure register renames
    px[0] = c[0].x; py[0] = c[0].y; pz[0] = c[0].z;
    px[1] = c[0].w; py[1] = c[1].x; pz[1] = c[1].y;
    px[2] = c[1].z; py[2] = c[1].w; pz[2] = c[2].x;
    px[3] = c[2].y; py[3] = c[2].z; pz[3] = c[2].w;
    px[4] = c[3].x; py[4] = c[3].y; pz[4] = c[3].z;
    px[5] = c[3].w; py[5] = c[4].x; pz[5] = c[4].y;
    px[6] = c[4].z; py[6] = c[4].w; pz[6] = c[5].x;
    px[7] = c[5].y; py[7] = c[5].z; pz[7] = c[5].w;

    unsigned long long m0[PPL], m1[PPL], any = 0;
    #pragma unroll
    for (int j = 0; j < PPL; ++j) {                  // 8 independent chains
        const float s = __fmaf_rn(pz[j], pz[j],
                          __fmaf_rn(py[j], py[j], __fmul_rn(px[j], px[j])));
        float t0 = __fmaf_rn(px[j], m2x0, s);
        t0 = __fmaf_rn(py[j], m2y0, t0);
        t0 = __fmaf_rn(pz[j], m2z0, t0);
        m0[j] = __ballot(t0 <= th0);
        float t1 = __fmaf_rn(px[j], m2x1, s);
        t1 = __fmaf_rn(py[j], m2y1, t1);
        t1 = __fmaf_rn(pz[j], m2z1, t1);
        m1[j] = __ballot(t1 <= th1);
        any |= m0[j] | m1[j];
    }
    if (any) {
        #pragma unroll
        for (int j = 0; j < PPL; ++j) {
            if (m0[j]) {                             // exact numpy distance
                const float dx = __fadd_rn(px[j], -qx0);
                const float dy = __fadd_rn(py[j], -qy0);
                const float dz = __fadd_rn(pz[j], -qz0);
                const float d  = __fadd_rn(
                    __fadd_rn(__fmul_rn(dx, dx), __fmul_rn(dy, dy)),
                    __fmul_rn(dz, dz));
                insert_all<0>(d, pb + j, lane, ld, li, tau0, th0, qnm0);
            }
        }
        #pragma unroll
        for (int j = 0; j < PPL; ++j) {
            if (m1[j]) {
                const float dx = __fadd_rn(px[j], -qx1);
                const float dy = __fadd_rn(py[j], -qy1);
                const float dz = __fadd_rn(pz[j], -qz1);
                const float d  = __fadd_rn(
                    __fadd_rn(__fmul_rn(dx, dx), __fmul_rn(dy, dy)),
                    __fmul_rn(dz, dz));
                insert_all<1>(d, pb + j, lane, ld, li, tau1, th1, qnm1);
            }
        }
    }
}

// No LDS, no barriers: 1.5 MB input is L2-resident. 1024 blocks x 4 waves.
// NO min-waves bound: its cap semantics forced VGPR 32/40 and spilled GBs
// in rounds 3-4; natural allocation (~70) is what we want.
__global__ __launch_bounds__(BLOCK) void knn_kernel(const float* __restrict__ xyz,
                                                    float* __restrict__ out_idx,
                                                    float* __restrict__ out_pts)
{
    const int tid  = threadIdx.x;
    const int lane = tid & 63;
    const int wv   = tid >> 6;
    const int w    = blockIdx.x * WPB + wv;          // wave id in [0, 4096)
    const int b    = w >> 10;
    const int pr   = w & 1023;                       // query pair
    const size_t base = (size_t)b * NPTS * 3;

    const int qp0 = pr << 5;                         // stride-16 subsample
    const float qx0 = xyz[base + 3 * qp0 + 0];
    const float qy0 = xyz[base + 3 * qp0 + 1];
    const float qz0 = xyz[base + 3 * qp0 + 2];
    const float qx1 = xyz[base + 3 * qp0 + 48];
    const float qy1 = xyz[base + 3 * qp0 + 49];
    const float qz1 = xyz[base + 3 * qp0 + 50];

    const int g0 = b * NQ + (pr << 1);
    if (lane == 0) {
        out_pts[3 * g0 + 0] = qx0;
        out_pts[3 * g0 + 1] = qy0;
        out_pts[3 * g0 + 2] = qz0;
        out_pts[3 * g0 + 3] = qx1;
        out_pts[3 * g0 + 4] = qy1;
        out_pts[3 * g0 + 5] = qz1;
    }

    // Gate constants: m2* = -2q*, qnm = -|q|^2 + margin.
    const float m2x0 = -2.0f * qx0, m2y0 = -2.0f * qy0, m2z0 = -2.0f * qz0;
    const float m2x1 = -2.0f * qx1, m2y1 = -2.0f * qy1, m2z1 = -2.0f * qz1;
    const float qnm0 = -(qx0 * qx0 + qy0 * qy0 + qz0 * qz0) + GATE_MARGIN;
    const float qnm1 = -(qx1 * qx1 + qy1 * qy1 + qz1 * qz1) + GATE_MARGIN;

    float ld = __builtin_inff();  int li = 0x7fffffff;
    float tau0 = __builtin_inff(), tau1 = __builtin_inff();
    float th0  = __builtin_inff(), th1  = __builtin_inff();

    // Lane's stream: 8 consecutive points (6 float4) per iteration.
    const float4* lp = (const float4*)(xyz + base) + 6 * lane;

    float4 A[6], Bf[6];
    load6(A, lp);                                    // prologue
    for (int k = 0; k < ITERS; k += 2) {             // double-buffered pipeline
        load6(Bf, lp + 384);                         // prefetch iter k+1
        step(A, (k << 9) + PPL * lane, lane,
             m2x0, m2y0, m2z0, m2x1, m2y1, m2z1,
             qx0, qy0, qz0, qx1, qy1, qz1,
             ld, li, tau0, tau1, th0, th1, qnm0, qnm1);
        if (k + 2 < ITERS)
            load6(A, lp + 768);                      // prefetch iter k+2
        step(Bf, ((k + 1) << 9) + PPL * lane, lane,
             m2x0, m2y0, m2z0, m2x1, m2y1, m2z1,
             qx0, qy0, qz0, qx1, qy1, qz1,
             ld, li, tau0, tau1, th0, th1, qnm0, qnm1);
        lp += 768;
    }

    // lanes 0..15: q0 ranks 0..15; lanes 16..31: q1 ranks (g1 = g0+1)
    if (lane < 2 * KNN) {
        out_idx[(size_t)g0 * KNN + lane] = (float)li;
    }
}

extern "C" void kernel_launch(void* const* d_in, const int* in_sizes, int n_in,
                              void* d_out, int out_size, void* d_ws, size_t ws_size,
                              hipStream_t stream) {
    const float* xyz = (const float*)d_in[0];
    float* out = (float*)d_out;
    float* out_idx = out;                                 // NB*NQ*KNN floats
    float* out_pts = out + (size_t)NB * NQ * KNN;         // NB*NQ*3 floats

    const int blocks = (NB * NQ / 2) / WPB;               // 1024
    knn_kernel<<<blocks, BLOCK, 0, stream>>>(xyz, out_idx, out_pts);
}